// Round 7
// baseline (236.573 us; speedup 1.0000x reference)
//
#include <hip/hip_runtime.h>
#include <stdint.h>

// ForwardTransformLayer: lifting step with circular 8-tap convolutions.
//   even = in[:, ::2], odd = in[:, 1::2]            (row length 8192 -> 4096 each)
//   odd_out[k]  = odd[k]  - sum_j even[(k-j) mod n] * wavelet[j]
//   even_out[k] = even[k] - sum_j odd[(k-j)  mod n] * scaling[j]
//   wavelet[j] = scaling_rec[7-j] * (j odd ? -1 : +1)
// d_out layout: even_out (rows*4096) then odd_out (rows*4096), row-major.
//
// R10 design: falsified so far -- traffic (R2), halo scheme (R3), occupancy/
// reg-pipelining (R4/R9), store cache policy (R6), instruction density (R7),
// wave lifetime (R8/R9). Clean profiled window (WRITE_SIZE == own bytes) at
// 2.5 TB/s with nothing saturated. The ONE mechanism common to all rounds:
// the per-wave VMEM->VGPR return + vmcnt dependency path. R10 swaps it for
// global_load_lds DMA (the +67% lever in the m97 GEMM ladder): each wave
// stages its 128-float4 window (halo+payload, circular wrap folded into the
// per-lane global address -- branchless, all 64 lanes active) into its own
// LDS segment, double-buffered, BARRIER-FREE: a wave reads only LDS it wrote
// itself, so a counted s_waitcnt vmcnt(2) replaces __syncthreads and the
// next tile's DMA stays in flight under the current tile's FMA+stores.
// ds_read_b128 at 16-B stride = 2 lanes/bank = conflict-free (m136).

#define COLS   8192
#define HALF   4096                 // pairs per row
#define F4R    2048                 // float4s per row
#define NT     256                  // threads per block
#define WPB    4                    // waves per block
#define TILES  16                   // row-slices per wave

typedef const __attribute__((address_space(1))) void* gas_t;
typedef __attribute__((address_space(3))) void*       las_t;

__global__ __launch_bounds__(NT) void fwd_dwt_kernel(
    const float* __restrict__ input,
    const float* __restrict__ scaling,
    const float* __restrict__ scaling_rec,
    float* __restrict__ out,
    int rows)
{
    // Per wave: 2 buffers x 128 float4 window (4 halo + 64 payload + 60 over-stage).
    __shared__ float4 lds4[2][WPB][128];

    const int lane = threadIdx.x & 63;
    const int widx = threadIdx.x >> 6;
    const int W    = blockIdx.x * WPB + widx;     // global wave id
    const int w32  = W & 31;                      // wave within its row (32 waves/row)
    const int row0 = W >> 5;                      // starting row
    const int F    = w32 * 64 + lane;             // row-local float4 index (fixed)

    // Per-lane row-local source indices for the two staging calls (constants;
    // circular wrap folded in -- call A covers window slots 0..63 = f4 base-4..+59,
    // call B covers slots 64..127 = f4 base+60..+123 (only 64..67 consumed)).
    const int ia = (w32 * 64 - 4 + lane) & (F4R - 1);
    const int ib = (w32 * 64 + 60 + lane) & (F4R - 1);

    const int rs = rows / TILES;                       // rows advanced per tile (256)
    const size_t instep = (size_t)rs * F4R;            // float4s per tile step

    const float4* gA = (const float4*)input + (size_t)row0 * F4R + ia;
    const float4* gB = (const float4*)input + (size_t)row0 * F4R + ib;

    // Filters (uniform -> SGPRs).
    float w[8], sc[8];
#pragma unroll
    for (int j = 0; j < 8; ++j) {
        w[j]  = scaling_rec[7 - j] * ((j & 1) ? -1.0f : 1.0f);
        sc[j] = scaling[j];
    }

    // Stage tile t into buffer buf: 2 DMA instructions, no VGPR round-trip.
    // LDS dest is wave-uniform base + lane*16 (HW rule), matching our layout.
    auto STAGE = [&](int buf, int t) {
        const float4* a = gA + (size_t)t * instep;
        const float4* b = gB + (size_t)t * instep;
        __builtin_amdgcn_global_load_lds((gas_t)(const void*)a,
                                         (las_t)(void*)&lds4[buf][widx][0],  16, 0, 0);
        __builtin_amdgcn_global_load_lds((gas_t)(const void*)b,
                                         (las_t)(void*)&lds4[buf][widx][64], 16, 0, 0);
    };

    float* oe = out + (size_t)row0 * HALF + 2 * F;     // even plane
    float* od = oe + (size_t)rows * HALF;              // odd plane
    const size_t ostep = (size_t)rs * HALF;

    STAGE(0, 0);

#pragma unroll 1
    for (int t = 0; t < TILES; ++t) {
        const int cur = t & 1;
        if (t + 1 < TILES) {
            STAGE(cur ^ 1, t + 1);
            // Retire tile t's 2 DMAs (and last tile's stores); leave tile
            // t+1's 2 DMAs in flight under this tile's compute.
            asm volatile("s_waitcnt vmcnt(2)" ::: "memory");
        } else {
            asm volatile("s_waitcnt vmcnt(0)" ::: "memory");
        }

        // Window: slots lane..lane+4 hold f4s F-4..F (pairs k0-8..k0+1), k0=2F.
        const float4 h4 = lds4[cur][widx][lane + 0];
        const float4 h3 = lds4[cur][widx][lane + 1];
        const float4 h2 = lds4[cur][widx][lane + 2];
        const float4 h1 = lds4[cur][widx][lane + 3];
        const float4 v  = lds4[cur][widx][lane + 4];

        float pe[9], po[9];
        pe[0] = h4.z; po[0] = h4.w;
        pe[1] = h3.x; po[1] = h3.y;  pe[2] = h3.z; po[2] = h3.w;
        pe[3] = h2.x; po[3] = h2.y;  pe[4] = h2.z; po[4] = h2.w;
        pe[5] = h1.x; po[5] = h1.y;  pe[6] = h1.z; po[6] = h1.w;
        pe[7] = v.x;  po[7] = v.y;   pe[8] = v.z;  po[8] = v.w;

        // even_out[k0+q] = pe[7+q] - sum_j po[7+q-j]*sc[j]   (q = 0,1)
        // odd_out [k0+q] = po[7+q] - sum_j pe[7+q-j]*w[j]
        float eo0 = pe[7], oo0 = po[7], eo1 = pe[8], oo1 = po[8];
#pragma unroll
        for (int j = 0; j < 8; ++j) {
            eo0 -= po[7 - j] * sc[j];
            oo0 -= pe[7 - j] * w[j];
            eo1 -= po[8 - j] * sc[j];
            oo1 -= pe[8 - j] * w[j];
        }

        // Dense stores: lane l writes 8 B at 8*l -> contiguous 512 B/wave.
        ((float2*)oe)[0] = make_float2(eo0, eo1);
        ((float2*)od)[0] = make_float2(oo0, oo1);
        oe += ostep; od += ostep;
    }
}

extern "C" void kernel_launch(void* const* d_in, const int* in_sizes, int n_in,
                              void* d_out, int out_size, void* d_ws, size_t ws_size,
                              hipStream_t stream) {
    const float* input       = (const float*)d_in[0];
    const float* scaling     = (const float*)d_in[1];
    const float* scaling_rec = (const float*)d_in[2];
    float*       out         = (float*)d_out;

    const int rows   = in_sizes[0] / COLS;                         // 4096
    const int blocks = (rows / TILES) * (F4R / 64) / WPB;          // 2048
    fwd_dwt_kernel<<<blocks, NT, 0, stream>>>(
        input, scaling, scaling_rec, out, rows);
}